// Round 1
// baseline (296.434 us; speedup 1.0000x reference)
//
#include <hip/hip_runtime.h>
#include <math.h>

// Problem constants (fixed by setup_inputs): N=4, K=11, H=W=256.
#define NB    4
#define KF    11
#define KK    121
#define HH    256
#define WW    256
#define HW    (HH * WW)
#define PADK  5
#define INVD  (1.0f / 255.0f)
#define GRID_P (NB * HH)         // 1024 blocks, one output row each
#define TW    268                // tile cols: 5 halo + 256 + 5 halo = 266, padded to 268 (16B-aligned rows)
#define TILE_FLOATS (2 * KF * TW)  // 5896 floats = 23.6 KB

// Layout per block: 256 threads = 4 ky-groups (g = t>>6) x 64 px-threads (p = t&63).
// Each px-thread owns 4 consecutive pixels (w0 = 4p, float4 F loads).
// Group g handles ky in {g, g+4, g+8} (group 3: 2 kys) -> per-thread load chain
// is 3 batches of 11 float4 (33 loads) instead of 121 float2.
// Partial sums combined across groups via LDS.

// Pass 1: m1 = filter_flow(grid, F).
__global__ __launch_bounds__(256, 4) void pass1_kernel(const float* __restrict__ F,
                                                       float* __restrict__ m1) {
    __shared__ float red[8 * 4 * 64];   // [c][g][p], c: 0-3 ax, 4-7 ay
    const int t  = threadIdx.x;
    const int n  = blockIdx.x >> 8;
    const int h  = blockIdx.x & 255;
    const int g  = t >> 6;              // wave-uniform (64 lanes per group)
    const int p  = t & 63;
    const int w0 = p * 4;

    // Column masks / masked x-coords for offsets o = q + kx in [0,13].
    float xv[14], mk[14];
#pragma unroll
    for (int o = 0; o < 14; ++o) {
        int c = w0 + o - PADK;
        bool in = (c >= 0 && c < WW);
        mk[o] = in ? 1.0f : 0.0f;
        xv[o] = in ? (float)c * INVD : 0.0f;
    }

    float ax[4] = {0, 0, 0, 0}, ay[4] = {0, 0, 0, 0};
    const float* fb = F + (size_t)n * KK * HW + (size_t)h * WW + w0;

#pragma unroll
    for (int i = 0; i < 3; ++i) {
        int ky = g + 4 * i;
        if (ky < KF) {
            int rr = h + ky - PADK;
            if (rr >= 0 && rr < HH) {           // wave-uniform; OOB row contributes 0
                float yv = (float)rr * INVD;
                const float* fr = fb + (size_t)(ky * KF) * HW;
                float4 f[KF];
#pragma unroll
                for (int kx = 0; kx < KF; ++kx)
                    f[kx] = *(const float4*)(fr + (size_t)kx * HW);
                float s[4] = {0, 0, 0, 0};
#pragma unroll
                for (int kx = 0; kx < KF; ++kx) {
                    float4 fk = f[kx];
#define TAP1(Q, FQ) \
                    ax[Q] = fmaf(FQ, xv[kx + Q], ax[Q]); \
                    s[Q]  = fmaf(FQ, mk[kx + Q], s[Q]);
                    TAP1(0, fk.x) TAP1(1, fk.y) TAP1(2, fk.z) TAP1(3, fk.w)
#undef TAP1
                }
#pragma unroll
                for (int q = 0; q < 4; ++q) ay[q] = fmaf(yv, s[q], ay[q]);
            }
        }
    }

    // Cross-group reduce via LDS: writes conflict-free (lane-contiguous).
#pragma unroll
    for (int q = 0; q < 4; ++q) {
        red[(q * 4 + g) * 64 + p]       = ax[q];
        red[((4 + q) * 4 + g) * 64 + p] = ay[q];
    }
    __syncthreads();
    // Thread t owns pixel w = t (p = t>>2, q = t&3).
    int q = t & 3, pp = t >> 2;
    float vx = 0.f, vy = 0.f;
#pragma unroll
    for (int gg = 0; gg < 4; ++gg) {
        vx += red[(q * 4 + gg) * 64 + pp];
        vy += red[((4 + q) * 4 + gg) * 64 + pp];
    }
    float* ob = m1 + (size_t)n * 2 * HW + (size_t)h * WW;
    ob[t]      = vx;
    ob[HW + t] = vy;
}

// Pass 2: m2 = filter_flow(m1in, F) -> loss; optionally fused pass1 for the
// other direction (single read of F serves both).
template <bool FUSE>
__global__ __launch_bounds__(256, 3) void pass2_kernel(const float* __restrict__ F,
                                                       const float* __restrict__ m1in,
                                                       float* __restrict__ m1out,
                                                       float* __restrict__ partial) {
    __shared__ float smem[TILE_FLOATS];  // tile [2][11][268]; reused for 16x4x64 reduce
    __shared__ float wsum[4];
    const int t  = threadIdx.x;
    const int n  = blockIdx.x >> 8;
    const int h  = blockIdx.x & 255;
    const int g  = t >> 6;
    const int p  = t & 63;
    const int w0 = p * 4;

    // Stage 11-row x 268-col x 2-ch m1in neighborhood (zero-padded halo).
    const float* mb = m1in + (size_t)n * 2 * HW;
    for (int i = t; i < TILE_FLOATS; i += 256) {
        int ch  = i / (KF * TW);
        int rem = i - ch * (KF * TW);
        int r   = rem / TW;
        int c   = rem - r * TW;
        int rr  = h + r - PADK;
        int cc  = c - PADK;
        float v = 0.0f;
        if (rr >= 0 && rr < HH && cc >= 0 && cc < WW)
            v = mb[(size_t)ch * HW + rr * WW + cc];
        smem[i] = v;
    }
    __syncthreads();

    float xv[14], mk[14];
    if (FUSE) {
#pragma unroll
        for (int o = 0; o < 14; ++o) {
            int c = w0 + o - PADK;
            bool in = (c >= 0 && c < WW);
            mk[o] = in ? 1.0f : 0.0f;
            xv[o] = in ? (float)c * INVD : 0.0f;
        }
    }

    float a1x[4] = {0, 0, 0, 0}, a1y[4] = {0, 0, 0, 0};
    float a2x[4] = {0, 0, 0, 0}, a2y[4] = {0, 0, 0, 0};
    const float* fb = F + (size_t)n * KK * HW + (size_t)h * WW + w0;

#pragma unroll
    for (int i = 0; i < 3; ++i) {
        int ky = g + 4 * i;
        if (ky < KF) {
            int rr = h + ky - PADK;
            if (rr >= 0 && rr < HH) {        // OOB row: tile zeros & padded grid -> skip
                float yv = (float)rr * INVD;
                const float* fr = fb + (size_t)(ky * KF) * HW;
                float4 f[KF];
#pragma unroll
                for (int kx = 0; kx < KF; ++kx)
                    f[kx] = *(const float4*)(fr + (size_t)kx * HW);

                // Register-cache this ky's tile span: cols w0..w0+13, both channels.
                const float* tx = smem + ky * TW + w0;   // 16B-aligned (TW%4==0, w0%4==0)
                const float* ty = tx + KF * TW;
                float cx[16], cy[16];
#pragma unroll
                for (int u = 0; u < 4; ++u) {
                    *(float4*)(cx + 4 * u) = *(const float4*)(tx + 4 * u);
                    *(float4*)(cy + 4 * u) = *(const float4*)(ty + 4 * u);
                }

                float s[4] = {0, 0, 0, 0};
#pragma unroll
                for (int kx = 0; kx < KF; ++kx) {
                    float4 fk = f[kx];
#define TAP2(Q, FQ) \
                    do { \
                        if (FUSE) { \
                            a1x[Q] = fmaf(FQ, xv[kx + Q], a1x[Q]); \
                            s[Q]   = fmaf(FQ, mk[kx + Q], s[Q]); \
                        } \
                        a2x[Q] = fmaf(FQ, cx[kx + Q], a2x[Q]); \
                        a2y[Q] = fmaf(FQ, cy[kx + Q], a2y[Q]); \
                    } while (0);
                    TAP2(0, fk.x) TAP2(1, fk.y) TAP2(2, fk.z) TAP2(3, fk.w)
#undef TAP2
                }
                if (FUSE) {
#pragma unroll
                    for (int q = 0; q < 4; ++q) a1y[q] = fmaf(yv, s[q], a1y[q]);
                }
            }
        }
    }

    // Cross-group reduce; reuse smem (all tile reads are done).
    __syncthreads();
#pragma unroll
    for (int q = 0; q < 4; ++q) {
        smem[(q * 4 + g) * 64 + p]        = a2x[q];
        smem[((4 + q) * 4 + g) * 64 + p]  = a2y[q];
        if (FUSE) {
            smem[((8 + q) * 4 + g) * 64 + p]  = a1x[q];
            smem[((12 + q) * 4 + g) * 64 + p] = a1y[q];
        }
    }
    __syncthreads();

    int q = t & 3, pp = t >> 2;
    float m2x = 0.f, m2y = 0.f, o1x = 0.f, o1y = 0.f;
#pragma unroll
    for (int gg = 0; gg < 4; ++gg) {
        m2x += smem[(q * 4 + gg) * 64 + pp];
        m2y += smem[((4 + q) * 4 + gg) * 64 + pp];
        if (FUSE) {
            o1x += smem[((8 + q) * 4 + gg) * 64 + pp];
            o1y += smem[((12 + q) * 4 + gg) * 64 + pp];
        }
    }
    if (FUSE) {
        float* ob = m1out + (size_t)n * 2 * HW + (size_t)h * WW;
        ob[t]      = o1x;
        ob[HW + t] = o1y;
    }

    float gx = (float)t * INVD, gy = (float)h * INVD;
    float dx = gx - m2x, dy = gy - m2y;
    float d = sqrtf(dx * dx + dy * dy);

    // block reduce -> one partial per block (no atomics, no zero-init needed)
#pragma unroll
    for (int off = 32; off > 0; off >>= 1) d += __shfl_down(d, off, 64);
    if ((t & 63) == 0) wsum[t >> 6] = d;
    __syncthreads();
    if (t == 0) partial[blockIdx.x] = wsum[0] + wsum[1] + wsum[2] + wsum[3];
}

__global__ __launch_bounds__(256) void finalize_kernel(const float* __restrict__ partial,
                                                       float* __restrict__ out) {
    __shared__ float wsum[4];
    int t = threadIdx.x;
    float s = 0.f;
#pragma unroll
    for (int i = 0; i < 8; ++i) s += partial[t + 256 * i];
#pragma unroll
    for (int off = 32; off > 0; off >>= 1) s += __shfl_down(s, off, 64);
    if ((t & 63) == 0) wsum[t >> 6] = s;
    __syncthreads();
    if (t == 0)
        out[0] = (wsum[0] + wsum[1] + wsum[2] + wsum[3]) * (1.0f / ((float)HW * (float)NB));
}

extern "C" void kernel_launch(void* const* d_in, const int* in_sizes, int n_in,
                              void* d_out, int out_size, void* d_ws, size_t ws_size,
                              hipStream_t stream) {
    const float* FA = (const float*)d_in[0];  // FF_AtoB
    const float* FB = (const float*)d_in[1];  // FF_BtoA
    float* out = (float*)d_out;

    float* m1A = (float*)d_ws;                       // [N,2,H,W] = 2 MB
    float* m1B = m1A + (size_t)NB * 2 * HW;          // [N,2,H,W] = 2 MB
    float* partial = m1B + (size_t)NB * 2 * HW;      // 2048 floats, all written every call

    dim3 grid(GRID_P), block(256);
    // m1_ABA = flow(grid, F_AtoB)
    pass1_kernel<<<grid, block, 0, stream>>>(FA, m1A);
    // single read of F_BtoA serves BOTH m2_ABA (-> loss) and m1_BAB
    pass2_kernel<true><<<grid, block, 0, stream>>>(FB, m1A, m1B, partial);
    // m2_BAB = flow(m1_BAB, F_AtoB) -> loss
    pass2_kernel<false><<<grid, block, 0, stream>>>(FA, m1B, nullptr, partial + GRID_P);

    finalize_kernel<<<1, block, 0, stream>>>(partial, out);
}

// Round 3
// 286.091 us; speedup vs baseline: 1.0362x; 1.0362x over previous
//
#include <hip/hip_runtime.h>
#include <math.h>

// Problem constants (fixed by setup_inputs): N=4, K=11, H=W=256.
#define NB    4
#define KF    11
#define KK    121
#define HH    256
#define WW    256
#define HW    (HH * WW)
#define PADK  5
#define INVD  (1.0f / 255.0f)
#define GRID_P (NB * HH)         // 1024 blocks, one output row each
#define TW    268                // tile cols: 5 halo + 256 + 5 halo = 266, padded to 268 (16B-aligned rows)
#define TILE_FLOATS (2 * KF * TW)  // 5896 floats = 23.6 KB

// F is streamed exactly once per pass and the MALL (L3) is full of dirty
// harness-poison between iterations: load F non-temporally so the stream
// does not allocate / evict dirty lines (avoids paying poison writeback
// bandwidth during the passes).
typedef float v4f __attribute__((ext_vector_type(4)));

__device__ __forceinline__ float4 ldnt4(const float* p) {
    v4f v = __builtin_nontemporal_load(reinterpret_cast<const v4f*>(p));
    return make_float4(v.x, v.y, v.z, v.w);
}

// Layout per block: 256 threads = 4 ky-groups (g = t>>6) x 64 px-threads (p = t&63).
// Each px-thread owns 4 consecutive pixels (w0 = 4p, float4 F loads).
// Group g handles ky in {g, g+4, g+8} (group 3: 2 kys).
// Partial sums combined across groups via LDS.

// Pass 1: m1 = filter_flow(grid, F).
__global__ __launch_bounds__(256, 4) void pass1_kernel(const float* __restrict__ F,
                                                       float* __restrict__ m1) {
    __shared__ float red[8 * 4 * 64];   // [c][g][p], c: 0-3 ax, 4-7 ay
    const int t  = threadIdx.x;
    const int n  = blockIdx.x >> 8;
    const int h  = blockIdx.x & 255;
    const int g  = t >> 6;              // wave-uniform (64 lanes per group)
    const int p  = t & 63;
    const int w0 = p * 4;

    // Column masks / masked x-coords for offsets o = q + kx in [0,13].
    float xv[14], mk[14];
#pragma unroll
    for (int o = 0; o < 14; ++o) {
        int c = w0 + o - PADK;
        bool in = (c >= 0 && c < WW);
        mk[o] = in ? 1.0f : 0.0f;
        xv[o] = in ? (float)c * INVD : 0.0f;
    }

    float ax[4] = {0, 0, 0, 0}, ay[4] = {0, 0, 0, 0};
    const float* fb = F + (size_t)n * KK * HW + (size_t)h * WW + w0;

#pragma unroll
    for (int i = 0; i < 3; ++i) {
        int ky = g + 4 * i;
        if (ky < KF) {
            int rr = h + ky - PADK;
            if (rr >= 0 && rr < HH) {           // wave-uniform; OOB row contributes 0
                float yv = (float)rr * INVD;
                const float* fr = fb + (size_t)(ky * KF) * HW;
                float4 f[KF];
#pragma unroll
                for (int kx = 0; kx < KF; ++kx)
                    f[kx] = ldnt4(fr + (size_t)kx * HW);
                float s[4] = {0, 0, 0, 0};
#pragma unroll
                for (int kx = 0; kx < KF; ++kx) {
                    float4 fk = f[kx];
#define TAP1(Q, FQ) \
                    ax[Q] = fmaf(FQ, xv[kx + Q], ax[Q]); \
                    s[Q]  = fmaf(FQ, mk[kx + Q], s[Q]);
                    TAP1(0, fk.x) TAP1(1, fk.y) TAP1(2, fk.z) TAP1(3, fk.w)
#undef TAP1
                }
#pragma unroll
                for (int q = 0; q < 4; ++q) ay[q] = fmaf(yv, s[q], ay[q]);
            }
        }
    }

    // Cross-group reduce via LDS: writes conflict-free (lane-contiguous).
#pragma unroll
    for (int q = 0; q < 4; ++q) {
        red[(q * 4 + g) * 64 + p]       = ax[q];
        red[((4 + q) * 4 + g) * 64 + p] = ay[q];
    }
    __syncthreads();
    // Thread t owns pixel w = t (p = t>>2, q = t&3).
    int q = t & 3, pp = t >> 2;
    float vx = 0.f, vy = 0.f;
#pragma unroll
    for (int gg = 0; gg < 4; ++gg) {
        vx += red[(q * 4 + gg) * 64 + pp];
        vy += red[((4 + q) * 4 + gg) * 64 + pp];
    }
    float* ob = m1 + (size_t)n * 2 * HW + (size_t)h * WW;
    ob[t]      = vx;
    ob[HW + t] = vy;
}

// Pass 2: m2 = filter_flow(m1in, F) -> loss; optionally fused pass1 for the
// other direction (single read of F serves both).
template <bool FUSE>
__global__ __launch_bounds__(256, 3) void pass2_kernel(const float* __restrict__ F,
                                                       const float* __restrict__ m1in,
                                                       float* __restrict__ m1out,
                                                       float* __restrict__ partial) {
    __shared__ float smem[TILE_FLOATS];  // tile [2][11][268]; reused for 16x4x64 reduce
    __shared__ float wsum[4];
    const int t  = threadIdx.x;
    const int n  = blockIdx.x >> 8;
    const int h  = blockIdx.x & 255;
    const int g  = t >> 6;
    const int p  = t & 63;
    const int w0 = p * 4;

    // Stage 11-row x 268-col x 2-ch m1in neighborhood (zero-padded halo).
    const float* mb = m1in + (size_t)n * 2 * HW;
    for (int i = t; i < TILE_FLOATS; i += 256) {
        int ch  = i / (KF * TW);
        int rem = i - ch * (KF * TW);
        int r   = rem / TW;
        int c   = rem - r * TW;
        int rr  = h + r - PADK;
        int cc  = c - PADK;
        float v = 0.0f;
        if (rr >= 0 && rr < HH && cc >= 0 && cc < WW)
            v = mb[(size_t)ch * HW + rr * WW + cc];
        smem[i] = v;
    }
    __syncthreads();

    float xv[14], mk[14];
    if (FUSE) {
#pragma unroll
        for (int o = 0; o < 14; ++o) {
            int c = w0 + o - PADK;
            bool in = (c >= 0 && c < WW);
            mk[o] = in ? 1.0f : 0.0f;
            xv[o] = in ? (float)c * INVD : 0.0f;
        }
    }

    float a1x[4] = {0, 0, 0, 0}, a1y[4] = {0, 0, 0, 0};
    float a2x[4] = {0, 0, 0, 0}, a2y[4] = {0, 0, 0, 0};
    const float* fb = F + (size_t)n * KK * HW + (size_t)h * WW + w0;

#pragma unroll
    for (int i = 0; i < 3; ++i) {
        int ky = g + 4 * i;
        if (ky < KF) {
            int rr = h + ky - PADK;
            if (rr >= 0 && rr < HH) {        // OOB row: tile zeros & padded grid -> skip
                float yv = (float)rr * INVD;
                const float* fr = fb + (size_t)(ky * KF) * HW;
                float4 f[KF];
#pragma unroll
                for (int kx = 0; kx < KF; ++kx)
                    f[kx] = ldnt4(fr + (size_t)kx * HW);

                // Register-cache this ky's tile span: cols w0..w0+13, both channels.
                const float* tx = smem + ky * TW + w0;   // 16B-aligned (TW%4==0, w0%4==0)
                const float* ty = tx + KF * TW;
                float cx[16], cy[16];
#pragma unroll
                for (int u = 0; u < 4; ++u) {
                    *(float4*)(cx + 4 * u) = *(const float4*)(tx + 4 * u);
                    *(float4*)(cy + 4 * u) = *(const float4*)(ty + 4 * u);
                }

                float s[4] = {0, 0, 0, 0};
#pragma unroll
                for (int kx = 0; kx < KF; ++kx) {
                    float4 fk = f[kx];
#define TAP2(Q, FQ) \
                    do { \
                        if (FUSE) { \
                            a1x[Q] = fmaf(FQ, xv[kx + Q], a1x[Q]); \
                            s[Q]   = fmaf(FQ, mk[kx + Q], s[Q]); \
                        } \
                        a2x[Q] = fmaf(FQ, cx[kx + Q], a2x[Q]); \
                        a2y[Q] = fmaf(FQ, cy[kx + Q], a2y[Q]); \
                    } while (0);
                    TAP2(0, fk.x) TAP2(1, fk.y) TAP2(2, fk.z) TAP2(3, fk.w)
#undef TAP2
                }
                if (FUSE) {
#pragma unroll
                    for (int q = 0; q < 4; ++q) a1y[q] = fmaf(yv, s[q], a1y[q]);
                }
            }
        }
    }

    // Cross-group reduce; reuse smem (all tile reads are done).
    __syncthreads();
#pragma unroll
    for (int q = 0; q < 4; ++q) {
        smem[(q * 4 + g) * 64 + p]        = a2x[q];
        smem[((4 + q) * 4 + g) * 64 + p]  = a2y[q];
        if (FUSE) {
            smem[((8 + q) * 4 + g) * 64 + p]  = a1x[q];
            smem[((12 + q) * 4 + g) * 64 + p] = a1y[q];
        }
    }
    __syncthreads();

    int q = t & 3, pp = t >> 2;
    float m2x = 0.f, m2y = 0.f, o1x = 0.f, o1y = 0.f;
#pragma unroll
    for (int gg = 0; gg < 4; ++gg) {
        m2x += smem[(q * 4 + gg) * 64 + pp];
        m2y += smem[((4 + q) * 4 + gg) * 64 + pp];
        if (FUSE) {
            o1x += smem[((8 + q) * 4 + gg) * 64 + pp];
            o1y += smem[((12 + q) * 4 + gg) * 64 + pp];
        }
    }
    if (FUSE) {
        float* ob = m1out + (size_t)n * 2 * HW + (size_t)h * WW;
        ob[t]      = o1x;
        ob[HW + t] = o1y;
    }

    float gx = (float)t * INVD, gy = (float)h * INVD;
    float dx = gx - m2x, dy = gy - m2y;
    float d = sqrtf(dx * dx + dy * dy);

    // block reduce -> one partial per block (no atomics, no zero-init needed)
#pragma unroll
    for (int off = 32; off > 0; off >>= 1) d += __shfl_down(d, off, 64);
    if ((t & 63) == 0) wsum[t >> 6] = d;
    __syncthreads();
    if (t == 0) partial[blockIdx.x] = wsum[0] + wsum[1] + wsum[2] + wsum[3];
}

__global__ __launch_bounds__(256) void finalize_kernel(const float* __restrict__ partial,
                                                       float* __restrict__ out) {
    __shared__ float wsum[4];
    int t = threadIdx.x;
    float s = 0.f;
#pragma unroll
    for (int i = 0; i < 8; ++i) s += partial[t + 256 * i];
#pragma unroll
    for (int off = 32; off > 0; off >>= 1) s += __shfl_down(s, off, 64);
    if ((t & 63) == 0) wsum[t >> 6] = s;
    __syncthreads();
    if (t == 0)
        out[0] = (wsum[0] + wsum[1] + wsum[2] + wsum[3]) * (1.0f / ((float)HW * (float)NB));
}

extern "C" void kernel_launch(void* const* d_in, const int* in_sizes, int n_in,
                              void* d_out, int out_size, void* d_ws, size_t ws_size,
                              hipStream_t stream) {
    const float* FA = (const float*)d_in[0];  // FF_AtoB
    const float* FB = (const float*)d_in[1];  // FF_BtoA
    float* out = (float*)d_out;

    float* m1A = (float*)d_ws;                       // [N,2,H,W] = 2 MB
    float* m1B = m1A + (size_t)NB * 2 * HW;          // [N,2,H,W] = 2 MB
    float* partial = m1B + (size_t)NB * 2 * HW;      // 2048 floats, all written every call

    dim3 grid(GRID_P), block(256);
    // m1_ABA = flow(grid, F_AtoB)
    pass1_kernel<<<grid, block, 0, stream>>>(FA, m1A);
    // single read of F_BtoA serves BOTH m2_ABA (-> loss) and m1_BAB
    pass2_kernel<true><<<grid, block, 0, stream>>>(FB, m1A, m1B, partial);
    // m2_BAB = flow(m1_BAB, F_AtoB) -> loss
    pass2_kernel<false><<<grid, block, 0, stream>>>(FA, m1B, nullptr, partial + GRID_P);

    finalize_kernel<<<1, block, 0, stream>>>(partial, out);
}